// Round 1
// baseline (238.116 us; speedup 1.0000x reference)
//
#include <hip/hip_runtime.h>

// RoPE fused with per-row max/min observation.
// x: (H=32, T=8192, D=128) fp32; cos/sin: (T, D) fp32.
// out[..., :64] = x1*c1 - x2*s1 ; out[..., 64:] = x2*c2 + x1*s2
// obs_max/obs_min: (H,T) row-wise max/min of out.
// scale_x / scale_cos / scale_sin are unused by the reference.
//
// R4 theory: kernel (~72 us, hidden under the harness's 83-us poison fills
// in rocprof top-5) is VMEM-instruction-rate bound, not HBM-bound (279 MB
// compulsory -> 44 us floor). Cut VMEM instrs per 16 rows 28 -> 18.5:
//  - 8 heads per 16-lane unit (cos/sin loaded once per 8 rows, waves halved)
//  - ONE 64-lane obs store replaces 8 lane0-masked scalar stores: after the
//    16-lane butterflies every lane holds all m[0..7]/n[0..7]; a 15-op
//    cndmask select tree (lane&7 = head, lane&8 = max/min) routes values,
//    obs_min = obs_max + H*T so a single base pointer serves both. Lanes
//    (l, l+16, l+32, l+48) write t..t+3 -> 16x coalesced 16B chunks.
//
// Mapping: 16 lanes per (t, head-group) unit; lane l owns float4 pair
// (elems 4l and 64+4l) of each of the 8 heads' rows. idx = tid>>4;
// t = idx & 8191 (fast-varying -> wave covers 4 consecutive t: x loads are
// 2KB-contiguous per head per wave across 2 instrs); hg = idx>>13 (0..3)
// picks heads 8hg..8hg+7. Nontemporal on streamed x/out; cached c/s loads.

#define HH 32
#define TT 8192
#define DD 128

typedef float vf4 __attribute__((ext_vector_type(4)));

__global__ __launch_bounds__(256) void rope_obs_kernel(
    const float* __restrict__ x,
    const float* __restrict__ cosp,
    const float* __restrict__ sinp,
    float* __restrict__ out,
    float* __restrict__ obsbuf)      // obs_max; obs_min at +HH*TT
{
    int tid  = blockIdx.x * blockDim.x + threadIdx.x;
    int lane = tid & 15;            // float4 index within first half of row
    int idx  = tid >> 4;            // [0, T * H/8)
    int t    = idx & (TT - 1);      // fast-varying for contiguity
    int hg   = idx >> 13;           // head group [0, 4)
    int h0   = hg << 3;             // first head of group (8 heads/group)

    const vf4* cr = (const vf4*)cosp + (size_t)t * 32;
    const vf4* sr = (const vf4*)sinp + (size_t)t * 32;
    vf4 c1 = cr[lane];
    vf4 c2 = cr[16 + lane];
    vf4 s1 = sr[lane];
    vf4 s2 = sr[16 + lane];

    const size_t hstride = (size_t)TT * 32;                 // vf4 per head
    size_t rowbase = ((size_t)h0 * TT + t) * 32;            // vf4 units
    const vf4* x4 = (const vf4*)x;
    vf4* o4 = (vf4*)out;

    // Issue all 16 x-loads up front for MLP (progressive vmcnt drain as
    // heads are consumed).
    vf4 xs1[8], xs2[8];
    #pragma unroll
    for (int i = 0; i < 8; ++i) {
        const vf4* xr = x4 + rowbase + (size_t)i * hstride;
        xs1[i] = __builtin_nontemporal_load(xr + lane);
        xs2[i] = __builtin_nontemporal_load(xr + 16 + lane);
    }

    float m[8], n[8];
    #pragma unroll
    for (int i = 0; i < 8; ++i) {
        vf4 x1 = xs1[i], x2 = xs2[i];
        vf4 o1, o2;
        o1.x = fmaf(x1.x, c1.x, -x2.x * s1.x);
        o1.y = fmaf(x1.y, c1.y, -x2.y * s1.y);
        o1.z = fmaf(x1.z, c1.z, -x2.z * s1.z);
        o1.w = fmaf(x1.w, c1.w, -x2.w * s1.w);
        o2.x = fmaf(x2.x, c2.x,  x1.x * s2.x);
        o2.y = fmaf(x2.y, c2.y,  x1.y * s2.y);
        o2.z = fmaf(x2.z, c2.z,  x1.z * s2.z);
        o2.w = fmaf(x2.w, c2.w,  x1.w * s2.w);

        vf4* orow = o4 + rowbase + (size_t)i * hstride;
        __builtin_nontemporal_store(o1, orow + lane);
        __builtin_nontemporal_store(o2, orow + 16 + lane);

        // Row max/min: 8 local elems, then 4-step butterfly over 16 lanes.
        // After the butterfly ALL 16 lanes hold the row result.
        float mx = fmaxf(fmaxf(fmaxf(o1.x, o1.y), fmaxf(o1.z, o1.w)),
                         fmaxf(fmaxf(o2.x, o2.y), fmaxf(o2.z, o2.w)));
        float mn = fminf(fminf(fminf(o1.x, o1.y), fminf(o1.z, o1.w)),
                         fminf(fminf(o2.x, o2.y), fminf(o2.z, o2.w)));
        #pragma unroll
        for (int sh = 8; sh >= 1; sh >>= 1) {
            mx = fmaxf(mx, __shfl_xor(mx, sh));
            mn = fminf(mn, __shfl_xor(mn, sh));
        }
        m[i] = mx;
        n[i] = mn;
    }

    // Single 64-lane obs store: lane l (0..15 within unit) handles
    // head (l&7), array (l>>3): 0 = max, 1 = min. Each lane stores for its
    // OWN t, so lanes {l, l+16, l+32, l+48} cover t..t+3 contiguously.
    // Compile-time cndmask select tree (no runtime register indexing).
    float a01 = (lane & 1) ? m[1] : m[0];
    float a23 = (lane & 1) ? m[3] : m[2];
    float a45 = (lane & 1) ? m[5] : m[4];
    float a67 = (lane & 1) ? m[7] : m[6];
    float b01 = (lane & 1) ? n[1] : n[0];
    float b23 = (lane & 1) ? n[3] : n[2];
    float b45 = (lane & 1) ? n[5] : n[4];
    float b67 = (lane & 1) ? n[7] : n[6];
    float a03 = (lane & 2) ? a23 : a01;
    float a47 = (lane & 2) ? a67 : a45;
    float b03 = (lane & 2) ? b23 : b01;
    float b47 = (lane & 2) ? b67 : b45;
    float am  = (lane & 4) ? a47 : a03;
    float bm  = (lane & 4) ? b47 : b03;
    float val = (lane & 8) ? bm  : am;

    size_t oidx = (size_t)(lane >> 3) * ((size_t)HH * TT)
                + (size_t)(h0 + (lane & 7)) * TT + (size_t)t;
    obsbuf[oidx] = val;
}

extern "C" void kernel_launch(void* const* d_in, const int* in_sizes, int n_in,
                              void* d_out, int out_size, void* d_ws, size_t ws_size,
                              hipStream_t stream) {
    const float* x    = (const float*)d_in[0];
    // d_in[1] = scale_x   (unused)
    const float* cosp = (const float*)d_in[2];
    // d_in[3] = scale_cos (unused)
    const float* sinp = (const float*)d_in[4];
    // d_in[5] = scale_sin (unused)

    float* out     = (float*)d_out;
    float* obs_max = out + (size_t)HH * TT * DD;           // 33,554,432
    // obs_min lives at obs_max + HH*TT; kernel addresses it via one base.

    const int total_threads = TT * 16 * (HH / 8);          // 524,288
    const int block = 256;
    const int grid  = total_threads / block;               // 2048

    rope_obs_kernel<<<grid, block, 0, stream>>>(x, cosp, sinp, out, obs_max);
}